// Round 8
// baseline (137.419 us; speedup 1.0000x reference)
//
#include <hip/hip_runtime.h>

// LBP for semantic dependency parsing — label-difference form, all 3
// iterations fused; F = e^s staged ONCE into LDS as fp16 (96 KB), per-thread
// register state ~nil (rounds 4-7 showed hipcc sheds any large per-thread
// payload to scratch/AGPR regardless of launch_bounds).
//
//   F[b,i,j,k] = 2^(log2e*s[b,i,j,k])             (only use of the scores)
//   D_1 = log2(p1 + F) - log2(1+p1),  p1 = 2^(-q0[i])
//   D_t = log2(p + F) - log2(1 + p),  p = 2^(D_{t-1} - q_{t-1}[i])
//   q_t[k] = q0[k] + mask[k] * sum_i D^sum_t[i,k] * mask[i]*(i!=j)*(i!=k)
//   out[b,k,j] = 1/(1+2^(-q_3[k]))
// Block (b,j) closes the whole recursion for column j. D is recomputed from
// the q-history (q0/q1/q2 in LDS) each pass.
//
// Geometry: 1024 thr; thread = (kg = t&15 -> k in [8kg,8kg+8), rg = t>>4 ->
// rows rg, rg+64). Staging: 2x global dwordx4 -> exp2 -> 1x ds_write_b128
// (fp16 half8) per row/tensor. Passes 2-3: ds_read_b128, conflict-free
// (wave's 64 lanes x 4 dwords cover all 32 banks evenly). Reduction:
// shfl_xor(16,32) folds the 4 rg-lanes holding the same k, then an 8 KB
// red array and a final 128-thread column sum.

#define TS 128

typedef float    f4v __attribute__((ext_vector_type(4)));
typedef float    f8v __attribute__((ext_vector_type(8)));
typedef _Float16 h8v __attribute__((ext_vector_type(8)));

constexpr float LOG2E = 1.4426950408889634f;

// ---- mask format probe: f[0]!=0 -> byte mask, f[1]!=0 -> float32, else int32
__global__ void flags_init(int* __restrict__ f) { f[0] = 0; f[1] = 0; }

__global__ void mask_detect(const unsigned char* __restrict__ m, int n, int* __restrict__ f) {
    int v1 = 0, v23 = 0;
    for (int i = blockIdx.x * blockDim.x + threadIdx.x; i < n; i += gridDim.x * blockDim.x) {
        const unsigned char b = m[i];           // first n bytes: in-bounds for all layouts
        const int r = i & 3;
        if (r == 1) v1 |= b;
        if (r >= 2) v23 |= b;
    }
    const int lane = threadIdx.x & 63;
    if (__any(v1)  && lane == 0) atomicOr(&f[0], 1);
    if (__any(v23) && lane == 0) atomicOr(&f[1], 1);
}

__device__ __forceinline__ float d_first(float F, float p1, float l1) {
    return __log2f(p1 + F) - l1;
}
__device__ __forceinline__ float d_next(float Dprev, float q, float F) {
    const float p = exp2f(fminf(Dprev - q, 126.0f));
    return __log2f(p + F) - __log2f(1.0f + p);
}

__global__ __launch_bounds__(1024, 4)
void lbp_fused(const float* __restrict__ s_edge,
               const f4v* __restrict__ sib4,
               const f4v* __restrict__ cop4,
               const f4v* __restrict__ grd4,
               const void* __restrict__ mask,
               const int* __restrict__ flags,
               float* __restrict__ outp)
{
    __shared__ _Float16 FsH[TS][TS];     // 32 KB each
    __shared__ _Float16 FcH[TS][TS];
    __shared__ _Float16 FgH[TS][TS];
    __shared__ float red[16][TS];        // 8 KB: [wave][k]
    __shared__ float q0s[TS], p1s[TS], lp1s[TS], q1s[TS], q2s[TS];
    __shared__ unsigned char mrow[TS];

    const int bj = blockIdx.x;
    const int b  = bj >> 7;
    const int j  = bj & (TS - 1);
    const int t  = threadIdx.x;
    const int kg = t & 15;               // k octet: k = 8kg .. 8kg+7
    const int rg = t >> 4;               // rows rg and rg+64
    const int k0 = kg * 8;
    const int lane = t & 63;
    const int wv = t >> 6;               // wave 0..15

    // ---- per-column prologue ----
    if (t < TS) {
        const int i = t;
        const int idx = (b * TS + i) * TS + j;
        const float q0 = LOG2E * s_edge[idx];
        q0s[i] = q0;
        const int f1 = flags[0], f23 = flags[1];
        unsigned char mv;
        if (f1)       mv = ((const unsigned char*)mask)[idx] != 0;
        else if (f23) mv = ((const float*)mask)[idx] != 0.0f;
        else          mv = ((const int*)mask)[idx]   != 0;
        mrow[i] = mv;
        const float p1 = exp2f(-q0);
        p1s[i]  = p1;
        lp1s[i] = __log2f(1.0f + p1);
    }
    __syncthreads();

    // float4 index of (b, i, j, k=8kg): colBase4 + i*(TS*TS/4)
    const size_t colBase4 = (size_t)b * (TS * TS * TS / 4) + (size_t)j * (TS / 4) + 2 * kg;

    float acc[8];
    #pragma unroll
    for (int c = 0; c < 8; ++c) acc[c] = 0.0f;

    // ---- staging fused with pass 1: global f32 -> F (exp2) -> fp16 LDS ----
    #pragma unroll
    for (int r = 0; r < 2; ++r) {
        const int i = rg + 64 * r;
        const size_t off = colBase4 + (size_t)i * (TS * TS / 4);
        const f4v vsa = sib4[off], vsb = sib4[off + 1];
        const f4v vca = cop4[off], vcb = cop4[off + 1];
        const f4v vga = grd4[off], vgb = grd4[off + 1];
        f8v fs, fc, fg;
        #pragma unroll
        for (int c = 0; c < 4; ++c) {
            fs[c] = exp2f(LOG2E * vsa[c]);  fs[c + 4] = exp2f(LOG2E * vsb[c]);
            fc[c] = exp2f(LOG2E * vca[c]);  fc[c + 4] = exp2f(LOG2E * vcb[c]);
            fg[c] = exp2f(LOG2E * vga[c]);  fg[c + 4] = exp2f(LOG2E * vgb[c]);
        }
        *(h8v*)&FsH[i][k0] = __builtin_convertvector(fs, h8v);
        *(h8v*)&FcH[i][k0] = __builtin_convertvector(fc, h8v);
        *(h8v*)&FgH[i][k0] = __builtin_convertvector(fg, h8v);
        const bool live = (mrow[i] != 0) && (i != j);
        if (live) {
            const float p1 = p1s[i], l1 = lp1s[i];
            #pragma unroll
            for (int c = 0; c < 8; ++c) {
                const float d = d_first(fs[c], p1, l1) + d_first(fc[c], p1, l1)
                              + d_first(fg[c], p1, l1);
                if (i != k0 + c) acc[c] += d;
            }
        }
    }
    // fold the 4 rg-lanes (stride 16) holding the same k
    #pragma unroll
    for (int c = 0; c < 8; ++c) {
        acc[c] += __shfl_xor(acc[c], 16);
        acc[c] += __shfl_xor(acc[c], 32);
    }
    if (lane < 16) {
        #pragma unroll
        for (int c = 0; c < 8; ++c) red[wv][lane * 8 + c] = acc[c];
    }
    __syncthreads();
    if (t < TS) {
        float tot = 0.0f;
        #pragma unroll
        for (int w = 0; w < 16; ++w) tot += red[w][t];
        q1s[t] = q0s[t] + (mrow[t] ? tot : 0.0f);
    }
    __syncthreads();

    // ---- pass 2: D1 from q0 (recomputed), update with q1 ----
    #pragma unroll
    for (int c = 0; c < 8; ++c) acc[c] = 0.0f;
    #pragma unroll
    for (int r = 0; r < 2; ++r) {
        const int i = rg + 64 * r;
        const bool live = (mrow[i] != 0) && (i != j);
        if (live) {
            const float p1 = p1s[i], l1 = lp1s[i], q1 = q1s[i];
            const f8v fs = __builtin_convertvector(*(const h8v*)&FsH[i][k0], f8v);
            const f8v fc = __builtin_convertvector(*(const h8v*)&FcH[i][k0], f8v);
            const f8v fg = __builtin_convertvector(*(const h8v*)&FgH[i][k0], f8v);
            #pragma unroll
            for (int c = 0; c < 8; ++c) {
                const float d = d_next(d_first(fs[c], p1, l1), q1, fs[c])
                              + d_next(d_first(fc[c], p1, l1), q1, fc[c])
                              + d_next(d_first(fg[c], p1, l1), q1, fg[c]);
                if (i != k0 + c) acc[c] += d;
            }
        }
    }
    #pragma unroll
    for (int c = 0; c < 8; ++c) {
        acc[c] += __shfl_xor(acc[c], 16);
        acc[c] += __shfl_xor(acc[c], 32);
    }
    if (lane < 16) {
        #pragma unroll
        for (int c = 0; c < 8; ++c) red[wv][lane * 8 + c] = acc[c];
    }
    __syncthreads();
    if (t < TS) {
        float tot = 0.0f;
        #pragma unroll
        for (int w = 0; w < 16; ++w) tot += red[w][t];
        q2s[t] = q0s[t] + (mrow[t] ? tot : 0.0f);
    }
    __syncthreads();

    // ---- pass 3: D1,D2 recomputed from q0,q1, update with q2 ----
    #pragma unroll
    for (int c = 0; c < 8; ++c) acc[c] = 0.0f;
    #pragma unroll
    for (int r = 0; r < 2; ++r) {
        const int i = rg + 64 * r;
        const bool live = (mrow[i] != 0) && (i != j);
        if (live) {
            const float p1 = p1s[i], l1 = lp1s[i], q1 = q1s[i], q2 = q2s[i];
            const f8v fs = __builtin_convertvector(*(const h8v*)&FsH[i][k0], f8v);
            const f8v fc = __builtin_convertvector(*(const h8v*)&FcH[i][k0], f8v);
            const f8v fg = __builtin_convertvector(*(const h8v*)&FgH[i][k0], f8v);
            #pragma unroll
            for (int c = 0; c < 8; ++c) {
                const float d = d_next(d_next(d_first(fs[c], p1, l1), q1, fs[c]), q2, fs[c])
                              + d_next(d_next(d_first(fc[c], p1, l1), q1, fc[c]), q2, fc[c])
                              + d_next(d_next(d_first(fg[c], p1, l1), q1, fg[c]), q2, fg[c]);
                if (i != k0 + c) acc[c] += d;
            }
        }
    }
    #pragma unroll
    for (int c = 0; c < 8; ++c) {
        acc[c] += __shfl_xor(acc[c], 16);
        acc[c] += __shfl_xor(acc[c], 32);
    }
    if (lane < 16) {
        #pragma unroll
        for (int c = 0; c < 8; ++c) red[wv][lane * 8 + c] = acc[c];
    }
    __syncthreads();
    if (t < TS) {
        float tot = 0.0f;
        #pragma unroll
        for (int w = 0; w < 16; ++w) tot += red[w][t];
        const float q3 = q0s[t] + (mrow[t] ? tot : 0.0f);
        outp[(b * TS + t) * TS + j] = 1.0f / (1.0f + exp2f(-q3));
    }
}

extern "C" void kernel_launch(void* const* d_in, const int* in_sizes, int n_in,
                              void* d_out, int out_size, void* d_ws, size_t ws_size,
                              hipStream_t stream) {
    const float* s_edge = (const float*)d_in[0];
    const f4v*   sib4   = (const f4v*)d_in[1];
    const f4v*   cop4   = (const f4v*)d_in[2];
    const f4v*   grd4   = (const f4v*)d_in[3];
    const void*  mask   = d_in[4];
    float* out = (float*)d_out;

    const int Bn = in_sizes[0] / (TS * TS);   // batch
    const int nMask = in_sizes[4];            // B*S*S elements

    int* flags = (int*)d_ws;

    flags_init<<<1, 1, 0, stream>>>(flags);
    mask_detect<<<64, 256, 0, stream>>>((const unsigned char*)mask, nMask, flags);
    lbp_fused<<<Bn * TS, 1024, 0, stream>>>(s_edge, sib4, cop4, grd4, mask, flags, out);
}